// Round 3
// baseline (911.084 us; speedup 1.0000x reference)
//
#include <hip/hip_runtime.h>
#include <math.h>

#define F_CH 12
#define C_DIM 200
#define C_HALF 100
#define HW 225
#define PERB (C_DIM*HW)      /* 45000 */
#define LN_EPS 1e-5f

/* ws layout (floats) */
#define WS_WT   0        /* 7200: wT[c][36] = {w11[:,c], w21[:,c], w31[:,c]} */
#define WS_DP   7200     /* 200:  D'[c] = d[c] - mean(d) */
#define WS_VARD 7400     /* 1:    mean(D'^2) */

__global__ __launch_bounds__(256) void k_prep(
    const float* __restrict__ w11, const float* __restrict__ w21,
    const float* __restrict__ w31, const float* __restrict__ b41,
    const float* __restrict__ w42, const float* __restrict__ b42,
    float* __restrict__ wT, float* __restrict__ Dp, float* __restrict__ varD)
{
    const int tid = threadIdx.x;
    for (int i = tid; i < 36*C_DIM; i += 256) {
        int c = i / 36, g = i - 36*c;
        float v;
        if (g < 12)      v = w11[g*C_DIM + c];
        else if (g < 24) v = w21[(g-12)*C_DIM + c];
        else             v = w31[(g-24)*C_DIM + c];
        wT[i] = v;
    }
    __shared__ float red[12];
    __shared__ float DmSh;
    float d = 0.f;
    if (tid < C_DIM) {
        float s = b42[tid];
#pragma unroll
        for (int j = 0; j < 6; ++j) s = fmaf(w42[tid*6+j], b41[j], s);
        d = s;
    }
    float s0 = d;
    for (int o = 32; o > 0; o >>= 1) s0 += __shfl_down(s0, o, 64);
    if ((tid & 63) == 0) red[tid >> 6] = s0;
    __syncthreads();
    if (tid == 0) DmSh = (red[0]+red[1]+red[2]+red[3]) * (1.f/C_DIM);
    __syncthreads();
    float dp = (tid < C_DIM) ? (d - DmSh) : 0.f;
    if (tid < C_DIM) Dp[tid] = dp;
    float s1 = dp*dp;
    for (int o = 32; o > 0; o >>= 1) s1 += __shfl_down(s1, o, 64);
    if ((tid & 63) == 0) red[4 + (tid >> 6)] = s1;
    __syncthreads();
    if (tid == 0) varD[0] = (red[4]+red[5]+red[6]+red[7]) * (1.f/C_DIM);
}

/* Fused, 512 threads/block: lower half (waves 0-3) convolves channels 0-99,
   upper half channels 100-199; 36 partial accumulators merged per pixel via
   conflict-free [36][226] LDS. Phase 2 also channel-split per half.
   launch_bounds(512,8): 4 blocks/CU x 8 waves = 32 waves/CU (100% occ). */
__global__ __launch_bounds__(512, 8) void k_fused(
    const float* __restrict__ X,
    const float* __restrict__ wT,
    const float* __restrict__ b11, const float* __restrict__ b21,
    const float* __restrict__ b31,
    const float* __restrict__ w41,
    const float* __restrict__ w42,
    const float* __restrict__ Dp, const float* __restrict__ varDp,
    const float* __restrict__ ln_g, const float* __restrict__ ln_b,
    float* __restrict__ out)
{
    const int b    = blockIdx.x;
    const int tid  = threadIdx.x;
    const int half = tid >> 8;        /* wave-uniform */
    const int lt   = tid & 255;

    __shared__ float M[36*226];       /* merge buffer [g][226], lane-stride-1 */
    __shared__ float PS[HW], RS[HW];
    __shared__ float vmb[F_CH];
    __shared__ float t1S[6];
    __shared__ float red[24];
    __shared__ float AmSh, varASh, covSh;
    __shared__ float AgS[C_DIM], DgS[C_DIM], blS[C_DIM];

    const float varD = varDp[0];

    float accK[F_CH], accQ[F_CH], accV[F_CH];
    if (half == 0) {
#pragma unroll
        for (int f = 0; f < F_CH; ++f) { accK[f] = b11[f]; accQ[f] = b21[f]; accV[f] = b31[f]; }
    } else {
#pragma unroll
        for (int f = 0; f < F_CH; ++f) { accK[f] = 0.f; accQ[f] = 0.f; accV[f] = 0.f; }
    }

    /* lanes >= 225 duplicate pixel 224 and are masked from stores/reductions */
    const int n = (lt < HW) ? lt : (HW-1);
    const float* xcol  = X  + (size_t)b*PERB + (size_t)(half*C_HALF)*HW + n;
    const float* wbase = wT + (size_t)(half*C_HALF)*36;

#define CONV_STEP(CBASE, XR)                                              \
    {                                                                     \
        const float* wr_ = wbase + (CBASE)*36;                            \
        _Pragma("unroll")                                                 \
        for (int u = 0; u < 4; ++u) {                                     \
            float xv_ = XR[u];                                            \
            const float* wu_ = wr_ + u*36;                                \
            _Pragma("unroll")                                             \
            for (int f = 0; f < F_CH; ++f) {                              \
                accK[f] = fmaf(xv_, wu_[f],    accK[f]);                  \
                accQ[f] = fmaf(xv_, wu_[12+f], accQ[f]);                  \
                accV[f] = fmaf(xv_, wu_[24+f], accV[f]);                  \
            }                                                             \
        }                                                                 \
    }

    /* depth-2 group prefetch: 8 X-loads in flight per wave */
    float xA[4], xB[4];
#pragma unroll
    for (int u = 0; u < 4; ++u) xA[u] = xcol[(size_t)u*HW];
#pragma unroll
    for (int u = 0; u < 4; ++u) xB[u] = xcol[(size_t)(4+u)*HW];
    for (int c = 0; c < C_HALF - 8; c += 4) {
        float xC[4];
        const float* xn4 = xcol + (size_t)(c+8)*HW;
#pragma unroll
        for (int u = 0; u < 4; ++u) xC[u] = xn4[(size_t)u*HW];
        CONV_STEP(c, xA);
#pragma unroll
        for (int u = 0; u < 4; ++u) { xA[u] = xB[u]; xB[u] = xC[u]; }
    }
    CONV_STEP(C_HALF-8, xA);
    CONV_STEP(C_HALF-4, xB);
#undef CONV_STEP

    if (tid < F_CH) vmb[tid] = 0.f;
    if (half == 1 && lt < HW) {
#pragma unroll
        for (int f = 0; f < F_CH; ++f) {
            M[f*226 + lt]      = accK[f];
            M[(12+f)*226 + lt] = accQ[f];
            M[(24+f)*226 + lt] = accV[f];
        }
    }
    __syncthreads();   /* B1: partials + vmb zero visible */

    float kq = 0.f;
    if (tid < HW) {    /* tid<225 => lower half; lt==tid */
#pragma unroll
        for (int f = 0; f < F_CH; ++f) {
            accK[f] += M[f*226 + tid];
            accQ[f] += M[(12+f)*226 + tid];
            accV[f] += M[(24+f)*226 + tid];
        }
#pragma unroll
        for (int f = 0; f < F_CH; ++f) kq = fmaf(accK[f], accQ[f], kq);

        /* vm bucketing: flat index m = 12*n + f -> bucket m/225 (raw-reshape scramble) */
        int m0 = 12*tid;
        int a0 = m0/225, a1 = (m0+11)/225;
        if (a0 == a1) {
            float s = 0.f;
#pragma unroll
            for (int f = 0; f < F_CH; ++f) s += accV[f];
            atomicAdd(&vmb[a0], s);
        } else {
            int split = 225*a1 - m0;
            float sa = 0.f, sb = 0.f;
#pragma unroll
            for (int f = 0; f < F_CH; ++f) { if (f < split) sa += accV[f]; else sb += accV[f]; }
            atomicAdd(&vmb[a0], sa);
            atomicAdd(&vmb[a1], sb);
        }
    }
    __syncthreads();   /* B2: vmb complete */

    if (tid == 0) {
        float v[F_CH], mx = -1e30f;
#pragma unroll
        for (int a = 0; a < F_CH; ++a) { v[a] = vmb[a]*(1.f/HW); mx = fmaxf(mx, v[a]); }
        float s = 0.f;
#pragma unroll
        for (int a = 0; a < F_CH; ++a) { v[a] = __expf(v[a]-mx); s += v[a]; }
        float inv = 1.f/s;
#pragma unroll
        for (int a = 0; a < F_CH; ++a) v[a] *= inv;
        /* fold t1 = w41 . vs here (same serial FMA chain as before) */
#pragma unroll
        for (int j = 0; j < 6; ++j) {
            float t = 0.f;
#pragma unroll
            for (int l = 0; l < F_CH; ++l) t = fmaf(w41[j*F_CH+l], v[l], t);
            t1S[j] = t;
        }
    }
    __syncthreads();   /* B3: t1S ready */

    float A = 0.f, AD = 0.f;
    if (tid < C_DIM) {
        float s = 0.f;
#pragma unroll
        for (int j = 0; j < 6; ++j) s = fmaf(w42[tid*6+j], t1S[j], s);
        A = s;
        AD = A * Dp[tid];
    }
    float r0 = A, r1 = A*A, r2 = AD;
    for (int o = 32; o > 0; o >>= 1) {
        r0 += __shfl_down(r0, o, 64);
        r1 += __shfl_down(r1, o, 64);
        r2 += __shfl_down(r2, o, 64);
    }
    if ((tid & 63) == 0) { int w = tid>>6; red[w*3]=r0; red[w*3+1]=r1; red[w*3+2]=r2; }
    __syncthreads();   /* B4 */
    if (tid == 0) {
        float S0 = 0.f, S1 = 0.f, S2 = 0.f;
#pragma unroll
        for (int w = 0; w < 8; ++w) { S0 += red[w*3]; S1 += red[w*3+1]; S2 += red[w*3+2]; }
        float Am = S0*(1.f/C_DIM);
        AmSh   = Am;
        varASh = S1*(1.f/C_DIM) - Am*Am;
        covSh  = S2*(1.f/C_DIM);
    }
    __syncthreads();   /* B5: stats ready */

    if (tid < C_DIM) {
        float g  = ln_g[tid];
        AgS[tid] = (A - AmSh)*g;
        DgS[tid] = Dp[tid]*g;
        blS[tid] = ln_b[tid];
    }
    if (tid < HW) {
        float var = fmaf(kq*kq, varASh, fmaf(2.f*kq, covSh, varD));
        float rs  = rsqrtf(var + LN_EPS);
        PS[tid] = kq*rs;
        RS[tid] = rs;
    }
    __syncthreads();   /* B6: params ready */

    /* phase 2: column-mode gate pass, channel-split per half.
       X re-reads are L2/L3 warm; params are wave-uniform LDS broadcasts;
       PS/RS reads are lane-stride-1 (conflict-free). */
    if (lt < HW) {
        float Pn = PS[lt], Rn = RS[lt];
        const int cofs = half*C_HALF;
        const float* __restrict__ xb = X   + (size_t)b*PERB + (size_t)cofs*HW + lt;
        float*       __restrict__ ob = out + (size_t)b*PERB + (size_t)cofs*HW + lt;
        float v0[4];
#pragma unroll
        for (int u = 0; u < 4; ++u) v0[u] = xb[(size_t)u*HW];
        for (int c = 0; c < C_HALF - 4; c += 4) {
            float nv[4];
            const float* xn4 = xb + (size_t)(c+4)*HW;
#pragma unroll
            for (int u = 0; u < 4; ++u) nv[u] = xn4[(size_t)u*HW];
#pragma unroll
            for (int u = 0; u < 4; ++u) {
                int cc = cofs + c + u;
                float xn   = fmaf(Pn, AgS[cc], fmaf(Rn, DgS[cc], blS[cc]));
                float gate = (xn > 0.f) ? (1.f/(1.f+__expf(-xn))) : 0.5f;
                __builtin_nontemporal_store(gate * v0[u], &ob[(size_t)(c+u)*HW]);
            }
#pragma unroll
            for (int u = 0; u < 4; ++u) v0[u] = nv[u];
        }
#pragma unroll
        for (int u = 0; u < 4; ++u) {
            int cc = cofs + C_HALF - 4 + u;
            float xn   = fmaf(Pn, AgS[cc], fmaf(Rn, DgS[cc], blS[cc]));
            float gate = (xn > 0.f) ? (1.f/(1.f+__expf(-xn))) : 0.5f;
            __builtin_nontemporal_store(gate * v0[u], &ob[(size_t)(C_HALF-4+u)*HW]);
        }
    }
}

extern "C" void kernel_launch(void* const* d_in, const int* in_sizes, int n_in,
                              void* d_out, int out_size, void* d_ws, size_t ws_size,
                              hipStream_t stream) {
    const float* X   = (const float*)d_in[0];
    const float* w11 = (const float*)d_in[1];
    const float* b11 = (const float*)d_in[2];
    const float* w21 = (const float*)d_in[3];
    const float* b21 = (const float*)d_in[4];
    const float* w31 = (const float*)d_in[5];
    const float* b31 = (const float*)d_in[6];
    const float* w41 = (const float*)d_in[7];
    const float* b41 = (const float*)d_in[8];
    const float* w42 = (const float*)d_in[9];
    const float* b42 = (const float*)d_in[10];
    const float* lng = (const float*)d_in[11];
    const float* lnb = (const float*)d_in[12];
    float* out = (float*)d_out;
    float* ws  = (float*)d_ws;

    float* wT = ws + WS_WT;
    float* Dp = ws + WS_DP;
    float* vD = ws + WS_VARD;

    hipLaunchKernelGGL(k_prep, dim3(1), dim3(256), 0, stream,
                       w11, w21, w31, b41, w42, b42, wT, Dp, vD);
    hipLaunchKernelGGL(k_fused, dim3(1024), dim3(512), 0, stream,
                       X, wT, b11, b21, b31, w41, w42, Dp, vD, lng, lnb, out);
}

// Round 4
// 600.520 us; speedup vs baseline: 1.5172x; 1.5172x over previous
//
#include <hip/hip_runtime.h>
#include <math.h>

#define F_CH 12
#define C_DIM 200
#define C_HALF 100
#define HW 225
#define PERB (C_DIM*HW)      /* 45000 */
#define LN_EPS 1e-5f

/* ws layout (floats) */
#define WS_WT   0        /* 7200: wT[c][36] = {w11[:,c], w21[:,c], w31[:,c]} */
#define WS_DP   7200     /* 200:  D'[c] = d[c] - mean(d) */
#define WS_VARD 7400     /* 1:    mean(D'^2) */

__global__ __launch_bounds__(256) void k_prep(
    const float* __restrict__ w11, const float* __restrict__ w21,
    const float* __restrict__ w31, const float* __restrict__ b41,
    const float* __restrict__ w42, const float* __restrict__ b42,
    float* __restrict__ wT, float* __restrict__ Dp, float* __restrict__ varD)
{
    const int tid = threadIdx.x;
    for (int i = tid; i < 36*C_DIM; i += 256) {
        int c = i / 36, g = i - 36*c;
        float v;
        if (g < 12)      v = w11[g*C_DIM + c];
        else if (g < 24) v = w21[(g-12)*C_DIM + c];
        else             v = w31[(g-24)*C_DIM + c];
        wT[i] = v;
    }
    __shared__ float red[12];
    __shared__ float DmSh;
    float d = 0.f;
    if (tid < C_DIM) {
        float s = b42[tid];
#pragma unroll
        for (int j = 0; j < 6; ++j) s = fmaf(w42[tid*6+j], b41[j], s);
        d = s;
    }
    float s0 = d;
    for (int o = 32; o > 0; o >>= 1) s0 += __shfl_down(s0, o, 64);
    if ((tid & 63) == 0) red[tid >> 6] = s0;
    __syncthreads();
    if (tid == 0) DmSh = (red[0]+red[1]+red[2]+red[3]) * (1.f/C_DIM);
    __syncthreads();
    float dp = (tid < C_DIM) ? (d - DmSh) : 0.f;
    if (tid < C_DIM) Dp[tid] = dp;
    float s1 = dp*dp;
    for (int o = 32; o > 0; o >>= 1) s1 += __shfl_down(s1, o, 64);
    if ((tid & 63) == 0) red[4 + (tid >> 6)] = s1;
    __syncthreads();
    if (tid == 0) varD[0] = (red[4]+red[5]+red[6]+red[7]) * (1.f/C_DIM);
}

/* Fused, 512 threads/block, accumulator-group split (18 regs/thread):
   waves 0-3 (half 0): acc = {K[0..11], Q[0..5]}  = wT cols  0..17
   waves 4-7 (half 1): acc = {Q[6..11], V[0..11]} = wT cols 18..35
   Both halves stream the SAME X addresses (2nd half hits L1/L2; FETCH
   unchanged); conv is perfectly balanced. Only Q[6..11] is exchanged
   via stride-1 LDS for kq. launch_bounds(512,4): 128-VGPR ceiling, no
   spill; natural ~45-reg allocation gives 8 waves/EU. */
__global__ __launch_bounds__(512, 4) void k_fused(
    const float* __restrict__ X,
    const float* __restrict__ wT,
    const float* __restrict__ b11, const float* __restrict__ b21,
    const float* __restrict__ b31,
    const float* __restrict__ w41,
    const float* __restrict__ w42,
    const float* __restrict__ Dp, const float* __restrict__ varDp,
    const float* __restrict__ ln_g, const float* __restrict__ ln_b,
    float* __restrict__ out)
{
    const int b    = blockIdx.x;
    const int tid  = threadIdx.x;
    const int half = tid >> 8;        /* wave-uniform */
    const int lt   = tid & 255;

    __shared__ float QbS[6*226];      /* Q[6..11] exchange, lane-stride-1 */
    __shared__ float PS[HW], RS[HW];
    __shared__ float vmb[F_CH];
    __shared__ float t1S[6];
    __shared__ float red[24];
    __shared__ float AmSh, varASh, covSh;
    __shared__ float AgS[C_DIM], DgS[C_DIM], blS[C_DIM];

    const float varD = varDp[0];

    float acc[18];
    if (half == 0) {
#pragma unroll
        for (int f = 0; f < 12; ++f) acc[f] = b11[f];
#pragma unroll
        for (int j = 0; j < 6; ++j)  acc[12+j] = b21[j];
    } else {
#pragma unroll
        for (int j = 0; j < 6; ++j)  acc[j] = b21[6+j];
#pragma unroll
        for (int f = 0; f < 12; ++f) acc[6+f] = b31[f];
    }

    if (tid < F_CH) vmb[tid] = 0.f;
    __syncthreads();   /* B0: vmb zeroed before half-1 atomics */

    /* lanes >= 225 duplicate pixel 224 and are masked from stores/reductions */
    const int n = (lt < HW) ? lt : (HW-1);
    const float* xcol  = X  + (size_t)b*PERB + n;
    const float* wbase = wT + half*18;

#define CONV_STEP(CBASE, XR)                                              \
    {                                                                     \
        const float* wr_ = wbase + (CBASE)*36;                            \
        _Pragma("unroll")                                                 \
        for (int u = 0; u < 4; ++u) {                                     \
            float xv_ = XR[u];                                            \
            const float* wu_ = wr_ + u*36;                                \
            _Pragma("unroll")                                             \
            for (int g = 0; g < 18; ++g)                                  \
                acc[g] = fmaf(xv_, wu_[g], acc[g]);                       \
        }                                                                 \
    }

    /* depth-2 group prefetch: 8 X-loads in flight per wave */
    float xA[4], xB[4];
#pragma unroll
    for (int u = 0; u < 4; ++u) xA[u] = xcol[(size_t)u*HW];
#pragma unroll
    for (int u = 0; u < 4; ++u) xB[u] = xcol[(size_t)(4+u)*HW];
    for (int c = 0; c < C_DIM - 8; c += 4) {
        float xC[4];
        const float* xn4 = xcol + (size_t)(c+8)*HW;
#pragma unroll
        for (int u = 0; u < 4; ++u) xC[u] = xn4[(size_t)u*HW];
        CONV_STEP(c, xA);
#pragma unroll
        for (int u = 0; u < 4; ++u) { xA[u] = xB[u]; xB[u] = xC[u]; }
    }
    CONV_STEP(C_DIM-8, xA);
    CONV_STEP(C_DIM-4, xB);
#undef CONV_STEP

    /* half 1: publish Q[6..11], do vm bucketing from V = acc[6..17] */
    if (half == 1 && lt < HW) {
#pragma unroll
        for (int j = 0; j < 6; ++j) QbS[j*226 + lt] = acc[j];

        /* vm bucketing: flat index m = 12*n + f -> bucket m/225 (raw-reshape scramble) */
        int m0 = 12*lt;
        int a0 = m0/225, a1 = (m0+11)/225;
        if (a0 == a1) {
            float s = 0.f;
#pragma unroll
            for (int f = 0; f < F_CH; ++f) s += acc[6+f];
            atomicAdd(&vmb[a0], s);
        } else {
            int split = 225*a1 - m0;
            float sa = 0.f, sb = 0.f;
#pragma unroll
            for (int f = 0; f < F_CH; ++f) { if (f < split) sa += acc[6+f]; else sb += acc[6+f]; }
            atomicAdd(&vmb[a0], sa);
            atomicAdd(&vmb[a1], sb);
        }
    }
    __syncthreads();   /* B1: QbS + vmb ready */

    /* half 0: kq in original f order (f=0..5 from regs, f=6..11 via QbS) */
    float kq = 0.f;
    if (half == 0 && lt < HW) {
#pragma unroll
        for (int f = 0; f < 6; ++f) kq = fmaf(acc[f], acc[12+f], kq);
#pragma unroll
        for (int j = 0; j < 6; ++j) kq = fmaf(acc[6+j], QbS[j*226 + lt], kq);
    }

    if (tid == 0) {
        float v[F_CH], mx = -1e30f;
#pragma unroll
        for (int a = 0; a < F_CH; ++a) { v[a] = vmb[a]*(1.f/HW); mx = fmaxf(mx, v[a]); }
        float s = 0.f;
#pragma unroll
        for (int a = 0; a < F_CH; ++a) { v[a] = __expf(v[a]-mx); s += v[a]; }
        float inv = 1.f/s;
#pragma unroll
        for (int a = 0; a < F_CH; ++a) v[a] *= inv;
#pragma unroll
        for (int j = 0; j < 6; ++j) {
            float t = 0.f;
#pragma unroll
            for (int l = 0; l < F_CH; ++l) t = fmaf(w41[j*F_CH+l], v[l], t);
            t1S[j] = t;
        }
    }
    __syncthreads();   /* B2: t1S ready */

    float A = 0.f, AD = 0.f;
    if (tid < C_DIM) {
        float s = 0.f;
#pragma unroll
        for (int j = 0; j < 6; ++j) s = fmaf(w42[tid*6+j], t1S[j], s);
        A = s;
        AD = A * Dp[tid];
    }
    float r0 = A, r1 = A*A, r2 = AD;
    for (int o = 32; o > 0; o >>= 1) {
        r0 += __shfl_down(r0, o, 64);
        r1 += __shfl_down(r1, o, 64);
        r2 += __shfl_down(r2, o, 64);
    }
    if ((tid & 63) == 0) { int w = tid>>6; red[w*3]=r0; red[w*3+1]=r1; red[w*3+2]=r2; }
    __syncthreads();   /* B3 */
    if (tid == 0) {
        float S0 = 0.f, S1 = 0.f, S2 = 0.f;
#pragma unroll
        for (int w = 0; w < 8; ++w) { S0 += red[w*3]; S1 += red[w*3+1]; S2 += red[w*3+2]; }
        float Am = S0*(1.f/C_DIM);
        AmSh   = Am;
        varASh = S1*(1.f/C_DIM) - Am*Am;
        covSh  = S2*(1.f/C_DIM);
    }
    __syncthreads();   /* B4: stats ready */

    if (tid < C_DIM) {
        float g  = ln_g[tid];
        AgS[tid] = (A - AmSh)*g;
        DgS[tid] = Dp[tid]*g;
        blS[tid] = ln_b[tid];
    }
    if (tid < HW) {    /* half-0 threads: kq valid */
        float var = fmaf(kq*kq, varASh, fmaf(2.f*kq, covSh, varD));
        float rs  = rsqrtf(var + LN_EPS);
        PS[tid] = kq*rs;
        RS[tid] = rs;
    }
    __syncthreads();   /* B5: params ready */

    /* phase 2: column-mode gate pass, channel-split per half.
       X re-reads are L2/L3 warm; params are wave-uniform LDS broadcasts;
       PS/RS reads are lane-stride-1 (conflict-free). */
    if (lt < HW) {
        float Pn = PS[lt], Rn = RS[lt];
        const int cofs = half*C_HALF;
        const float* __restrict__ xb = X   + (size_t)b*PERB + (size_t)cofs*HW + lt;
        float*       __restrict__ ob = out + (size_t)b*PERB + (size_t)cofs*HW + lt;
        float v0[4];
#pragma unroll
        for (int u = 0; u < 4; ++u) v0[u] = xb[(size_t)u*HW];
        for (int c = 0; c < C_HALF - 4; c += 4) {
            float nv[4];
            const float* xn4 = xb + (size_t)(c+4)*HW;
#pragma unroll
            for (int u = 0; u < 4; ++u) nv[u] = xn4[(size_t)u*HW];
#pragma unroll
            for (int u = 0; u < 4; ++u) {
                int cc = cofs + c + u;
                float xn   = fmaf(Pn, AgS[cc], fmaf(Rn, DgS[cc], blS[cc]));
                float gate = (xn > 0.f) ? (1.f/(1.f+__expf(-xn))) : 0.5f;
                __builtin_nontemporal_store(gate * v0[u], &ob[(size_t)(c+u)*HW]);
            }
#pragma unroll
            for (int u = 0; u < 4; ++u) v0[u] = nv[u];
        }
#pragma unroll
        for (int u = 0; u < 4; ++u) {
            int cc = cofs + C_HALF - 4 + u;
            float xn   = fmaf(Pn, AgS[cc], fmaf(Rn, DgS[cc], blS[cc]));
            float gate = (xn > 0.f) ? (1.f/(1.f+__expf(-xn))) : 0.5f;
            __builtin_nontemporal_store(gate * v0[u], &ob[(size_t)(C_HALF-4+u)*HW]);
        }
    }
}

extern "C" void kernel_launch(void* const* d_in, const int* in_sizes, int n_in,
                              void* d_out, int out_size, void* d_ws, size_t ws_size,
                              hipStream_t stream) {
    const float* X   = (const float*)d_in[0];
    const float* w11 = (const float*)d_in[1];
    const float* b11 = (const float*)d_in[2];
    const float* w21 = (const float*)d_in[3];
    const float* b21 = (const float*)d_in[4];
    const float* w31 = (const float*)d_in[5];
    const float* b31 = (const float*)d_in[6];
    const float* w41 = (const float*)d_in[7];
    const float* b41 = (const float*)d_in[8];
    const float* w42 = (const float*)d_in[9];
    const float* b42 = (const float*)d_in[10];
    const float* lng = (const float*)d_in[11];
    const float* lnb = (const float*)d_in[12];
    float* out = (float*)d_out;
    float* ws  = (float*)d_ws;

    float* wT = ws + WS_WT;
    float* Dp = ws + WS_DP;
    float* vD = ws + WS_VARD;

    hipLaunchKernelGGL(k_prep, dim3(1), dim3(256), 0, stream,
                       w11, w21, w31, b41, w42, b42, wT, Dp, vD);
    hipLaunchKernelGGL(k_fused, dim3(1024), dim3(512), 0, stream,
                       X, wT, b11, b21, b31, w41, w42, Dp, vD, lng, lnb, out);
}